// Round 7
// baseline (257.820 us; speedup 1.0000x reference)
//
#include <hip/hip_runtime.h>
#include <hip/hip_bf16.h>
#include <hip/hip_fp16.h>
#include <math.h>

#define BIGF 1e8f
#define BIGS 28672.0f   // invalid-cell sentinel in fp16 cost matrix

__device__ inline float min3f(float a, float b, float c) {
    float d;
    asm("v_min3_f32 %0, %1, %2, %3" : "=v"(d) : "v"(a), "v"(b), "v"(c));
    return d;
}
// D = f32(lo/hi half of pw) * 1.0f + c   (fused fp16 convert + add)
__device__ inline float addh_lo(unsigned pw, float c) {
    float d;
    asm("v_fma_mix_f32 %0, %1, 1.0, %2 op_sel:[0,0,0] op_sel_hi:[1,0,0]"
        : "=v"(d) : "v"(pw), "v"(c));
    return d;
}
__device__ inline float addh_hi(unsigned pw, float c) {
    float d;
    asm("v_fma_mix_f32 %0, %1, 1.0, %2 op_sel:[1,0,0] op_sel_hi:[1,0,0]"
        : "=v"(d) : "v"(pw), "v"(c));
    return d;
}

// async global -> LDS, 16 B per lane (one instruction stages 1 KB per wave)
__device__ __forceinline__ void dma16(const void* g,
        __attribute__((address_space(3))) unsigned int* l) {
    __builtin_amdgcn_global_load_lds(
        (const __attribute__((address_space(1))) unsigned int*)g, l, 16, 0, 0);
}

// ---------------------------------------------------------------------------
// prep_kernel: unchanged (proven, absmax 0.0).
// blocks 0..255: fp16 cost matrix, diagonal-major, W-transform fold (D+2,
// cell (0,0) stores plain D00). blocks 256..1278: fill invalid slots of one
// diagonal with BIGS.
// ---------------------------------------------------------------------------
__global__ __launch_bounds__(256) void prep_kernel(
        const float* __restrict__ pred, const float* __restrict__ targ,
        __half* __restrict__ Dh) {
    const int bid = blockIdx.x;
    const int t   = threadIdx.x;

    if (bid < 256) {
        const int b  = bid >> 6;
        const int i0 = ((bid >> 3) & 7) * 64;
        const int j0 = (bid & 7) * 64;
        __shared__ float sp[64][81];
        __shared__ float st[64][81];

        const float4* __restrict__ p4 = (const float4*)(pred + ((size_t)b * 512 + i0) * 80);
        const float4* __restrict__ t4 = (const float4*)(targ + ((size_t)b * 512 + j0) * 80);
        #pragma unroll
        for (int q = 0; q < 5; ++q) {
            int idx = q * 256 + t;       // 0..1279
            int r = idx / 20, dq = idx % 20;
            float4 v = p4[r * 20 + dq];
            sp[r][dq*4+0]=v.x; sp[r][dq*4+1]=v.y; sp[r][dq*4+2]=v.z; sp[r][dq*4+3]=v.w;
            float4 w = t4[r * 20 + dq];
            st[r][dq*4+0]=w.x; st[r][dq*4+1]=w.y; st[r][dq*4+2]=w.z; st[r][dq*4+3]=w.w;
        }
        __syncthreads();

        const int tx = t & 15, ty = t >> 4;
        float acc[4][4];
        #pragma unroll
        for (int r = 0; r < 4; ++r)
            #pragma unroll
            for (int c = 0; c < 4; ++c) acc[r][c] = 0.f;

        #pragma unroll 4
        for (int d = 0; d < 80; ++d) {
            float a0 = sp[4*ty+0][d], a1 = sp[4*ty+1][d], a2 = sp[4*ty+2][d], a3 = sp[4*ty+3][d];
            float b0 = st[4*tx+0][d], b1 = st[4*tx+1][d], b2 = st[4*tx+2][d], b3 = st[4*tx+3][d];
            acc[0][0] += fabsf(a0-b0); acc[0][1] += fabsf(a0-b1); acc[0][2] += fabsf(a0-b2); acc[0][3] += fabsf(a0-b3);
            acc[1][0] += fabsf(a1-b0); acc[1][1] += fabsf(a1-b1); acc[1][2] += fabsf(a1-b2); acc[1][3] += fabsf(a1-b3);
            acc[2][0] += fabsf(a2-b0); acc[2][1] += fabsf(a2-b1); acc[2][2] += fabsf(a2-b2); acc[2][3] += fabsf(a2-b3);
            acc[3][0] += fabsf(a3-b0); acc[3][1] += fabsf(a3-b1); acc[3][2] += fabsf(a3-b2); acc[3][3] += fabsf(a3-b3);
        }

        #pragma unroll
        for (int r = 0; r < 4; ++r) {
            #pragma unroll
            for (int c = 0; c < 4; ++c) {
                int i = i0 + 4*ty + r;
                int j = j0 + 4*tx + c;
                float v = acc[r][c];
                float w = ((i | j) == 0) ? v : (v + 2.0f);   // W-transform fold
                Dh[((size_t)b * 1023 + (i + j)) * 512 + i] = __float2half(w);
            }
        }
    } else {
        const int k  = bid - 256;               // 0..1022
        const int lo = (k > 511) ? (k - 511) : 0;
        const int hi = (k < 511) ? k : 511;
        const __half big = __float2half(BIGS);
        #pragma unroll
        for (int b = 0; b < 4; ++b) {
            __half* row = Dh + ((size_t)b * 1023 + k) * 512;
            int i1 = t;
            int i2 = t + 256;
            if (i1 < lo || i1 > hi) row[i1] = big;
            if (i2 < lo || i2 > hi) row[i2] = big;
        }
    }
}

// ---------------------------------------------------------------------------
// dp_kernel: soft-DTW wavefront DP (min3 + W-transform, fp16 costs).
// HBM -> LDS 32-slot ring via global_load_lds (zero VGPR cost, allocator
// can't shrink it); counted s_waitcnt vmcnt(28) gates consumption (never 0
// in the main loop). LDS -> regs via 4-deep ds_read_b128 stage (3 ahead).
// Per step: 1 DMA + 1 ds_read + 2 DPP + 8 min3 + 8 fma_mix + 1 add.
// ---------------------------------------------------------------------------
#define DPPSHR(x) __int_as_float(__builtin_amdgcn_update_dpp(                 \
        __float_as_int(BIGF), __float_as_int(x), 0x138, 0xF, 0xF, false))

#define STEP(V1, V2, Q)                                                       \
  {                                                                           \
    float nb1 = DPPSHR(V1[7]);                                                \
    float nb2 = DPPSHR(V2[7]);                                                \
    V2[7] = addh_hi(Q.w, min3f(V2[6], V1[6], V1[7]));                         \
    V2[6] = addh_lo(Q.w, min3f(V2[5], V1[5], V1[6]));                         \
    V2[5] = addh_hi(Q.z, min3f(V2[4], V1[4], V1[5]));                         \
    V2[4] = addh_lo(Q.z, min3f(V2[3], V1[3], V1[4]));                         \
    V2[3] = addh_hi(Q.y, min3f(V2[2], V1[2], V1[3]));                         \
    V2[2] = addh_lo(Q.y, min3f(V2[1], V1[1], V1[2]));                         \
    V2[1] = addh_hi(Q.x, min3f(V2[0], V1[0], V1[1]));                         \
    V2[0] = addh_lo(Q.x, min3f(nb2,   nb1,   V1[0]));                         \
  }

__global__ __launch_bounds__(128, 1) void dp_kernel(
        const __half* __restrict__ Dh,
        const float* __restrict__ ldp, const int* __restrict__ dt,
        float* __restrict__ out) {
    __shared__ alignas(16) unsigned char smem[32 * 1024];
    const int tid = threadIdx.x;
    if (tid >= 64) {
        if (blockIdx.x == 0) {
            const int l = tid - 64;
            float s = 0.f;
            #pragma unroll
            for (int q = 0; q < 8; ++q) {
                int idx = l * 8 + q;
                s += fabsf(ldp[idx] - logf((float)dt[idx] + 1.0f));
            }
            #pragma unroll
            for (int o = 32; o > 0; o >>= 1) s += __shfl_down(s, o);
            if (l == 0) atomicAdd(out, s * (1.0f / 512.0f));
        }
        return;
    }

    const int b    = blockIdx.x;
    const int lane = tid;
    const char* __restrict__ gb = (const char*)(Dh + (size_t)b * 1023 * 512);
    const unsigned laneoff = (unsigned)lane * 16u;
    const unsigned smoff   = (unsigned)(uintptr_t)&smem[0];

#define S3(slot) ((__attribute__((address_space(3))) unsigned int*)(smoff + (unsigned)(slot) * 1024u))
#define QREAD(slot) (*(const uint4*)(smem + (unsigned)(slot) * 1024u + laneoff))

    float A[8], B[8];
    #pragma unroll
    for (int r = 0; r < 8; ++r) { A[r] = BIGF; B[r] = BIGF; }

    // peeled step k=0: only cell (0,0) valid; W_0[0] = D00 (stored w/o +2)
    {
        float c00 = __half2float(*(const __half*)gb);
        B[0] = (lane == 0) ? c00 : BIGF;
    }
    asm volatile("" :: "v"(B[0]));                     // materialize before fence
    asm volatile("s_waitcnt vmcnt(0)" ::: "memory");   // clean vmcnt baseline

    // prologue: DMA diagonals 1..32 into ring slots (slot = diag & 31)
    unsigned voff = laneoff + 1024u;
    #pragma unroll
    for (int d = 1; d <= 32; ++d) {
        dma16(gb + voff, S3(d & 31));
        voff += 1024u;
    }
    asm volatile("s_waitcnt vmcnt(29)" ::: "memory");  // diagonals 1..3 resident
    uint4 Q0 = QREAD(1);
    uint4 Q1 = QREAD(2);
    uint4 Q2 = QREAD(3);
    uint4 Q3;

    // main loop: k = 1..992 (31 groups x 32 phases). step k = 1+32t+p.
    // consume Q[p&3] (diag k); ds_read diag k+3 -> Q[(p+3)&3] from slot
    // (p+4)&31; DMA diag k+32 -> slot (p+1)&31. wait vmcnt(28) => diag k+3
    // resident (28 newer DMAs may be outstanding).
    for (int t = 0; t < 31; ++t) {
#define PH(p, Vx, Vy, Qc, Qn)                                                 \
        asm volatile("s_waitcnt vmcnt(28)" ::: "memory");                     \
        Qn = QREAD(((p) + 4) & 31);                                           \
        STEP(Vx, Vy, Qc)                                                      \
        dma16(gb + voff, S3(((p) + 1) & 31));                                 \
        voff += 1024u;
#define PH4(p0)                                                               \
        PH(p0 + 0, B, A, Q0, Q3)                                              \
        PH(p0 + 1, A, B, Q1, Q0)                                              \
        PH(p0 + 2, B, A, Q2, Q1)                                              \
        PH(p0 + 3, A, B, Q3, Q2)
        PH4(0) PH4(4) PH4(8) PH4(12) PH4(16) PH4(20) PH4(24) PH4(28)
#undef PH4
#undef PH
    }

    // tail: k = 993..1022 (30 steps). All remaining diagonals resident after
    // vmcnt(0). ds_read continues 3 ahead while diag k+3 <= 1022 (p2 <= 26).
    asm volatile("s_waitcnt vmcnt(0)" ::: "memory");
#define TP(p, Vx, Vy, Qc, Qn)                                                 \
        Qn = QREAD(((p) + 4) & 31);                                           \
        STEP(Vx, Vy, Qc)
    TP(0,B,A,Q0,Q3)  TP(1,A,B,Q1,Q0)  TP(2,B,A,Q2,Q1)  TP(3,A,B,Q3,Q2)
    TP(4,B,A,Q0,Q3)  TP(5,A,B,Q1,Q0)  TP(6,B,A,Q2,Q1)  TP(7,A,B,Q3,Q2)
    TP(8,B,A,Q0,Q3)  TP(9,A,B,Q1,Q0)  TP(10,B,A,Q2,Q1) TP(11,A,B,Q3,Q2)
    TP(12,B,A,Q0,Q3) TP(13,A,B,Q1,Q0) TP(14,B,A,Q2,Q1) TP(15,A,B,Q3,Q2)
    TP(16,B,A,Q0,Q3) TP(17,A,B,Q1,Q0) TP(18,B,A,Q2,Q1) TP(19,A,B,Q3,Q2)
    TP(20,B,A,Q0,Q3) TP(21,A,B,Q1,Q0) TP(22,B,A,Q2,Q1) TP(23,A,B,Q3,Q2)
    TP(24,B,A,Q0,Q3) TP(25,A,B,Q1,Q0) TP(26,B,A,Q2,Q1)
    STEP(A,B,Q3)   // k=1020
    STEP(B,A,Q0)   // k=1021
    STEP(A,B,Q1)   // k=1022
#undef TP

    // k=1022 (even) wrote B; cell (511,511) = lane 63, r=7. Undo W-transform.
    if (lane == 63) atomicAdd(out, (B[7] - 1022.0f) * (1.0f / 2048.0f));
}

extern "C" void kernel_launch(void* const* d_in, const int* in_sizes, int n_in,
                              void* d_out, int out_size, void* d_ws, size_t ws_size,
                              hipStream_t stream) {
    const float* pred = (const float*)d_in[0];   // mel_pred  [4,512,80]
    const float* targ = (const float*)d_in[1];   // mel_target[4,512,80]
    const float* ldp  = (const float*)d_in[2];   // log_d_pred[4,128]
    const int*   dt   = (const int*)d_in[3];     // d_target  [4,128]
    float* out = (float*)d_out;

    __half* Dh = (__half*)d_ws;                  // 4*1023*512 halves = 4.19 MB

    hipMemsetAsync(out, 0, sizeof(float), stream);
    prep_kernel<<<256 + 1023, 256, 0, stream>>>(pred, targ, Dh);
    dp_kernel<<<4, 128, 0, stream>>>(Dh, ldp, dt, out);
}

// Round 8
// 68.024 us; speedup vs baseline: 3.7901x; 3.7901x over previous
//
#include <hip/hip_runtime.h>
#include <hip/hip_bf16.h>
#include <hip/hip_fp16.h>
#include <math.h>

#define BIGF 1e8f
#define BIGS 28672.0f   // invalid-cell sentinel in fp16 cost matrix

__device__ inline float min3f(float a, float b, float c) {
    float d;
    asm("v_min3_f32 %0, %1, %2, %3" : "=v"(d) : "v"(a), "v"(b), "v"(c));
    return d;
}
// D = f32(lo/hi half of pw) * 1.0f + c   (fused fp16 convert + add)
__device__ inline float addh_lo(unsigned pw, float c) {
    float d;
    asm("v_fma_mix_f32 %0, %1, 1.0, %2 op_sel:[0,0,0] op_sel_hi:[1,0,0]"
        : "=v"(d) : "v"(pw), "v"(c));
    return d;
}
__device__ inline float addh_hi(unsigned pw, float c) {
    float d;
    asm("v_fma_mix_f32 %0, %1, 1.0, %2 op_sel:[1,0,0] op_sel_hi:[1,0,0]"
        : "=v"(d) : "v"(pw), "v"(c));
    return d;
}

// ---------------------------------------------------------------------------
// prep_kernel: unchanged (proven, absmax 0.0).
// blocks 0..255: fp16 cost matrix, diagonal-major, W-transform fold (D+2,
// cell (0,0) stores plain D00). blocks 256..1278: fill invalid slots of one
// diagonal with BIGS.
// ---------------------------------------------------------------------------
__global__ __launch_bounds__(256) void prep_kernel(
        const float* __restrict__ pred, const float* __restrict__ targ,
        __half* __restrict__ Dh) {
    const int bid = blockIdx.x;
    const int t   = threadIdx.x;

    if (bid < 256) {
        const int b  = bid >> 6;
        const int i0 = ((bid >> 3) & 7) * 64;
        const int j0 = (bid & 7) * 64;
        __shared__ float sp[64][81];
        __shared__ float st[64][81];

        const float4* __restrict__ p4 = (const float4*)(pred + ((size_t)b * 512 + i0) * 80);
        const float4* __restrict__ t4 = (const float4*)(targ + ((size_t)b * 512 + j0) * 80);
        #pragma unroll
        for (int q = 0; q < 5; ++q) {
            int idx = q * 256 + t;       // 0..1279
            int r = idx / 20, dq = idx % 20;
            float4 v = p4[r * 20 + dq];
            sp[r][dq*4+0]=v.x; sp[r][dq*4+1]=v.y; sp[r][dq*4+2]=v.z; sp[r][dq*4+3]=v.w;
            float4 w = t4[r * 20 + dq];
            st[r][dq*4+0]=w.x; st[r][dq*4+1]=w.y; st[r][dq*4+2]=w.z; st[r][dq*4+3]=w.w;
        }
        __syncthreads();

        const int tx = t & 15, ty = t >> 4;
        float acc[4][4];
        #pragma unroll
        for (int r = 0; r < 4; ++r)
            #pragma unroll
            for (int c = 0; c < 4; ++c) acc[r][c] = 0.f;

        #pragma unroll 4
        for (int d = 0; d < 80; ++d) {
            float a0 = sp[4*ty+0][d], a1 = sp[4*ty+1][d], a2 = sp[4*ty+2][d], a3 = sp[4*ty+3][d];
            float b0 = st[4*tx+0][d], b1 = st[4*tx+1][d], b2 = st[4*tx+2][d], b3 = st[4*tx+3][d];
            acc[0][0] += fabsf(a0-b0); acc[0][1] += fabsf(a0-b1); acc[0][2] += fabsf(a0-b2); acc[0][3] += fabsf(a0-b3);
            acc[1][0] += fabsf(a1-b0); acc[1][1] += fabsf(a1-b1); acc[1][2] += fabsf(a1-b2); acc[1][3] += fabsf(a1-b3);
            acc[2][0] += fabsf(a2-b0); acc[2][1] += fabsf(a2-b1); acc[2][2] += fabsf(a2-b2); acc[2][3] += fabsf(a2-b3);
            acc[3][0] += fabsf(a3-b0); acc[3][1] += fabsf(a3-b1); acc[3][2] += fabsf(a3-b2); acc[3][3] += fabsf(a3-b3);
        }

        #pragma unroll
        for (int r = 0; r < 4; ++r) {
            #pragma unroll
            for (int c = 0; c < 4; ++c) {
                int i = i0 + 4*ty + r;
                int j = j0 + 4*tx + c;
                float v = acc[r][c];
                float w = ((i | j) == 0) ? v : (v + 2.0f);   // W-transform fold
                Dh[((size_t)b * 1023 + (i + j)) * 512 + i] = __float2half(w);
            }
        }
    } else {
        const int k  = bid - 256;               // 0..1022
        const int lo = (k > 511) ? (k - 511) : 0;
        const int hi = (k < 511) ? k : 511;
        const __half big = __float2half(BIGS);
        #pragma unroll
        for (int b = 0; b < 4; ++b) {
            __half* row = Dh + ((size_t)b * 1023 + k) * 512;
            int i1 = t;
            int i2 = t + 256;
            if (i1 < lo || i1 > hi) row[i1] = big;
            if (i2 < lo || i2 > hi) row[i2] = big;
        }
    }
}

// ---------------------------------------------------------------------------
// dp_kernel: soft-DTW wavefront DP (min3 + W-transform, fp16 costs).
// 16 NAMED uint4 ring slots (64 VGPRs, honestly allocatable), asm-volatile
// global_load_dwordx4 in 4-bursts with literal offsets. ONE s_waitcnt
// vmcnt(12) per 4 steps (+ sched_barrier(0), rule #18) -> oldest 4 slots
// resident; slack 12-16 slots * ~45cy/step >= HBM/L3 latency.
// Per step: 2 DPP + 8 v_min3_f32 + 8 v_fma_mix_f32.
// ---------------------------------------------------------------------------
#define DPPSHR(x) __int_as_float(__builtin_amdgcn_update_dpp(                 \
        __float_as_int(BIGF), __float_as_int(x), 0x138, 0xF, 0xF, false))

#define STEP(V1, V2, Q)                                                       \
  {                                                                           \
    float nb1 = DPPSHR(V1[7]);                                                \
    float nb2 = DPPSHR(V2[7]);                                                \
    V2[7] = addh_hi(Q.w, min3f(V2[6], V1[6], V1[7]));                         \
    V2[6] = addh_lo(Q.w, min3f(V2[5], V1[5], V1[6]));                         \
    V2[5] = addh_hi(Q.z, min3f(V2[4], V1[4], V1[5]));                         \
    V2[4] = addh_lo(Q.z, min3f(V2[3], V1[3], V1[4]));                         \
    V2[3] = addh_hi(Q.y, min3f(V2[2], V1[2], V1[3]));                         \
    V2[2] = addh_lo(Q.y, min3f(V2[1], V1[1], V1[2]));                         \
    V2[1] = addh_hi(Q.x, min3f(V2[0], V1[0], V1[1]));                         \
    V2[0] = addh_lo(Q.x, min3f(nb2,   nb1,   V1[0]));                         \
  }

#define GL(Qd, off)                                                           \
    asm volatile("global_load_dwordx4 %0, %1, %2 offset:" #off               \
                 : "=v"(Qd) : "v"(voff), "s"(gb));

#define WAITSB(n)                                                             \
    asm volatile("s_waitcnt vmcnt(" #n ")" ::: "memory");                     \
    __builtin_amdgcn_sched_barrier(0);

__global__ __launch_bounds__(128, 1) void dp_kernel(
        const __half* __restrict__ Dh,
        const float* __restrict__ ldp, const int* __restrict__ dt,
        float* __restrict__ out) {
    const int tid = threadIdx.x;
    if (tid >= 64) {
        if (blockIdx.x == 0) {
            const int l = tid - 64;
            float s = 0.f;
            #pragma unroll
            for (int q = 0; q < 8; ++q) {
                int idx = l * 8 + q;
                s += fabsf(ldp[idx] - logf((float)dt[idx] + 1.0f));
            }
            #pragma unroll
            for (int o = 32; o > 0; o >>= 1) s += __shfl_down(s, o);
            if (l == 0) atomicAdd(out, s * (1.0f / 512.0f));
        }
        return;
    }

    const int b    = blockIdx.x;
    const int lane = tid;
    const char* __restrict__ gb = (const char*)(Dh + (size_t)b * 1023 * 512);

    float A[8], B[8];
    #pragma unroll
    for (int r = 0; r < 8; ++r) { A[r] = BIGF; B[r] = BIGF; }

    // peeled step k=0: only cell (0,0) valid; W_0[0] = D00 (stored w/o +2)
    {
        float c00 = __half2float(*(const __half*)gb);
        B[0] = (lane == 0) ? c00 : BIGF;
    }
    asm volatile("" :: "v"(B[0]));                     // materialize before fence
    asm volatile("s_waitcnt vmcnt(0)" ::: "memory");   // clean vmcnt baseline

    uint4 Q00, Q01, Q02, Q03, Q04, Q05, Q06, Q07;
    uint4 Q08, Q09, Q10, Q11, Q12, Q13, Q14, Q15;

    // prologue: load diagonals 1..16 into slots 0..15 (slot = (diag-1)&15)
    unsigned voff = (unsigned)lane * 16u + 1024u;
    GL(Q00, 0) GL(Q01, 1024) GL(Q02, 2048) GL(Q03, 3072) voff += 4096u;
    GL(Q04, 0) GL(Q05, 1024) GL(Q06, 2048) GL(Q07, 3072) voff += 4096u;
    GL(Q08, 0) GL(Q09, 1024) GL(Q10, 2048) GL(Q11, 3072) voff += 4096u;
    GL(Q12, 0) GL(Q13, 1024) GL(Q14, 2048) GL(Q15, 3072) voff += 4096u;
    // voff now points at diagonal 17

    // sub-group: wait oldest-4, 4 steps, refill 4 slots
#define SG(Qa, Qb, Qc, Qd)                                                    \
    WAITSB(12)                                                                \
    STEP(B, A, Qa) STEP(A, B, Qb) STEP(B, A, Qc) STEP(A, B, Qd)               \
    GL(Qa, 0) GL(Qb, 1024) GL(Qc, 2048) GL(Qd, 3072) voff += 4096u;

    // main: 62 groups x 16 steps = k 1..992; issues diagonals 17..1008
    for (int g = 0; g < 62; ++g) {
        SG(Q00, Q01, Q02, Q03)
        SG(Q04, Q05, Q06, Q07)
        SG(Q08, Q09, Q10, Q11)
        SG(Q12, Q13, Q14, Q15)
    }
#undef SG

    // special group: k = 993..1008, issue diagonals 1009..1022 (14 loads)
    WAITSB(12)
    STEP(B, A, Q00) STEP(A, B, Q01) STEP(B, A, Q02) STEP(A, B, Q03)
    GL(Q00, 0) GL(Q01, 1024) GL(Q02, 2048) GL(Q03, 3072) voff += 4096u;
    WAITSB(12)
    STEP(B, A, Q04) STEP(A, B, Q05) STEP(B, A, Q06) STEP(A, B, Q07)
    GL(Q04, 0) GL(Q05, 1024) GL(Q06, 2048) GL(Q07, 3072) voff += 4096u;
    WAITSB(12)
    STEP(B, A, Q08) STEP(A, B, Q09) STEP(B, A, Q10) STEP(A, B, Q11)
    GL(Q08, 0) GL(Q09, 1024) GL(Q10, 2048) GL(Q11, 3072) voff += 4096u;
    WAITSB(12)
    STEP(B, A, Q12) STEP(A, B, Q13) STEP(B, A, Q14) STEP(A, B, Q15)
    GL(Q12, 0) GL(Q13, 1024)   // diagonals 1021, 1022 — last valid

    // tail: k = 1009..1022 (14 steps) from slots 0..13
    WAITSB(0)
    STEP(B, A, Q00) STEP(A, B, Q01) STEP(B, A, Q02) STEP(A, B, Q03)
    STEP(B, A, Q04) STEP(A, B, Q05) STEP(B, A, Q06) STEP(A, B, Q07)
    STEP(B, A, Q08) STEP(A, B, Q09) STEP(B, A, Q10) STEP(A, B, Q11)
    STEP(B, A, Q12) STEP(A, B, Q13)

    // k=1022 (even) wrote B; cell (511,511) = lane 63, r=7. Undo W-transform.
    if (lane == 63) atomicAdd(out, (B[7] - 1022.0f) * (1.0f / 2048.0f));
}

extern "C" void kernel_launch(void* const* d_in, const int* in_sizes, int n_in,
                              void* d_out, int out_size, void* d_ws, size_t ws_size,
                              hipStream_t stream) {
    const float* pred = (const float*)d_in[0];   // mel_pred  [4,512,80]
    const float* targ = (const float*)d_in[1];   // mel_target[4,512,80]
    const float* ldp  = (const float*)d_in[2];   // log_d_pred[4,128]
    const int*   dt   = (const int*)d_in[3];     // d_target  [4,128]
    float* out = (float*)d_out;

    __half* Dh = (__half*)d_ws;                  // 4*1023*512 halves = 4.19 MB

    hipMemsetAsync(out, 0, sizeof(float), stream);
    prep_kernel<<<256 + 1023, 256, 0, stream>>>(pred, targ, Dh);
    dp_kernel<<<4, 128, 0, stream>>>(Dh, ldp, dt, out);
}